// Round 3
// baseline (276.272 us; speedup 1.0000x reference)
//
#include <hip/hip_runtime.h>
#include <stdint.h>

#define B_ 2048
#define T_ 256
#define V_ 128
#define E_ 128
#define H_ 64
#define G4_ 256  // 4*H
#define POS_W 20.0f

typedef _Float16 half1;
typedef _Float16 half2_t __attribute__((ext_vector_type(2)));

#if __has_builtin(__builtin_amdgcn_exp2f)
#define EXP2F(x) __builtin_amdgcn_exp2f(x)
#else
#define EXP2F(x) exp2f(x)
#endif

#if __has_builtin(__builtin_amdgcn_rcpf)
#define RCPF(x) __builtin_amdgcn_rcpf(x)
#else
#define RCPF(x) (1.0f / (x))
#endif

__device__ __forceinline__ half2_t bchalf2(uint32_t u) {
    return __builtin_bit_cast(half2_t, u);
}

// Inline-asm dot2: "v" constraints force BOTH operands into arch VGPRs at every
// use. R1/R2 evidence: with the builtin, the compiler kept the 128-reg weight
// array in AGPRs (VGPR_Count=84 at any launch_bounds; no scratch traffic) and
// paid ~220 extra VALU instrs/step in v_accvgpr_read copies -> 800 cyc/step.
__device__ __forceinline__ float fdot2(half2_t a, half2_t b, float c) {
    float d;
    asm("v_dot2_f32_f16 %0, %1, %2, %3" : "=v"(d) : "v"(a), "v"(b), "v"(c));
    return d;
}

__device__ __forceinline__ float sigm(float x) {
    // 1/(1+2^(-x*log2e)); saturates correctly at +-inf (rcp(inf)=0)
    return RCPF(1.0f + EXP2F(-1.44269504f * x));
}

__device__ __forceinline__ float tanhr(float x) {
    // tanh(x) = 1 - 2/(e^(2x)+1); exp2 under/overflow saturates to -1/+1, no clamp
    float t = EXP2F(2.88539008f * x);
    return 1.0f - 2.0f * RCPF(t + 1.0f);
}

// ---------------------------------------------------------------------------
// Kernel 1 (fused prep):
//  blocks [0,128):  proj[v][l*4+g] = dot(emb[v], W_ih[g*64+l]) + b_ih + b_hh (f32)
//  blocks [128,160): repack W_hh [256,64] f32 -> half2, lane-major:
//    flat n = l*128 + g*32 + j  <-  (W_hh[g*64+l][2j], W_hh[g*64+l][2j+1])
//  block 128, tid 0 additionally zeroes the loss accumulator out[2048].
// ---------------------------------------------------------------------------
__global__ void k_prep(const float* __restrict__ emb, const float* __restrict__ Wih,
                       const float* __restrict__ bih, const float* __restrict__ bhh,
                       const float* __restrict__ Whh,
                       float* __restrict__ proj, uint32_t* __restrict__ whh,
                       float* __restrict__ loss_slot) {
    int tid = threadIdx.x;  // 0..255
    if (blockIdx.x < V_) {
        int v = blockIdx.x;
        int l = tid >> 2, g = tid & 3;
        int row = g * 64 + l;
        const float4* e4 = (const float4*)(emb + v * E_);
        const float4* w4 = (const float4*)(Wih + row * E_);
        float acc = bih[row] + bhh[row];
#pragma unroll
        for (int i = 0; i < E_ / 4; ++i) {
            float4 a = e4[i];
            float4 b = w4[i];
            acc += a.x * b.x + a.y * b.y + a.z * b.z + a.w * b.w;
        }
        proj[v * G4_ + tid] = acc;  // coalesced: addr = v*256 + tid
    } else {
        if (blockIdx.x == V_ && tid == 0) *loss_slot = 0.0f;
        int n = (blockIdx.x - V_) * 256 + tid;  // 0..8191
        int j = n & 31;
        int g = (n >> 5) & 3;
        int l = n >> 7;
        int row = g * 64 + l;
        half2_t h2 = {(half1)Whh[row * H_ + 2 * j], (half1)Whh[row * H_ + 2 * j + 1]};
        whh[n] = __builtin_bit_cast(uint32_t, h2);
    }
}

// ---------------------------------------------------------------------------
// Kernel 2: recurrence + logits + fused loss term. One wave per batch element.
// Lane L owns hidden unit L: carries c[L]; computes 4 gate dots for unit L via
// asm v_dot2_f32_f16 against f16 W_hh pinned in arch VGPRs. Dot accumulators
// start at the fp32 input projection (saves converts+adds). h exchanged
// through a 128B LDS broadcast buffer (single wave -> lockstep, no barrier).
// ---------------------------------------------------------------------------
__launch_bounds__(64, 1)
__global__ void k_lstm(const int* __restrict__ x, const uint32_t* __restrict__ whh,
                       const float* __restrict__ proj, const float* __restrict__ Wfc,
                       const float* __restrict__ bfc, const float* __restrict__ targets,
                       float* __restrict__ logits, float* __restrict__ loss_slot) {
    int b = blockIdx.x;
    int L = threadIdx.x;  // 0..63

    __shared__ __align__(16) uint32_t hbuf[32];  // 64 halves: h[0..63]
    __shared__ int xrow[T_];

#pragma unroll
    for (int i = 0; i < T_ / 64; ++i) xrow[i * 64 + L] = x[b * T_ + i * 64 + L];
    if (L < 32) hbuf[L] = 0u;  // h0 = 0
    __syncthreads();

    // lane L's W_hh slice: 128 half2 = 128 VGPRs, fully unrolled constant idx
    half2_t w[4][32];
    {
        const uint4* wb4 = (const uint4*)(whh + L * 128);
#pragma unroll
        for (int i = 0; i < 32; ++i) {
            uint4 q = wb4[i];
            int n = i * 4;
            w[(n + 0) >> 5][(n + 0) & 31] = bchalf2(q.x);
            w[(n + 1) >> 5][(n + 1) & 31] = bchalf2(q.y);
            w[(n + 2) >> 5][(n + 2) & 31] = bchalf2(q.z);
            w[(n + 3) >> 5][(n + 3) & 31] = bchalf2(q.w);
        }
    }

    float c = 0.0f;
    float h = 0.0f;

    // software-pipelined input projection (one step ahead), fp32 (i,f,g,o)
    int v0 = xrow[0];
    float4 pu = *(const float4*)(proj + v0 * G4_ + L * 4);

    const uint4* hb4 = (const uint4*)hbuf;
    half1* hb16 = (half1*)&hbuf[0];

    for (int t = 0; t < T_; ++t) {
        int vn = xrow[(t + 1) & (T_ - 1)];
        float4 pn = *(const float4*)(proj + vn * G4_ + L * 4);

        // accumulators start at the input projection
        float ai = pu.x, af = pu.y, ag = pu.z, ao = pu.w;
#pragma unroll
        for (int q = 0; q < 8; ++q) {
            uint4 hh = hb4[q];  // broadcast ds_read_b128 (uniform address)
            half2_t hv0 = bchalf2(hh.x), hv1 = bchalf2(hh.y);
            half2_t hv2 = bchalf2(hh.z), hv3 = bchalf2(hh.w);
            ai = fdot2(w[0][q * 4 + 0], hv0, ai);
            af = fdot2(w[1][q * 4 + 0], hv0, af);
            ag = fdot2(w[2][q * 4 + 0], hv0, ag);
            ao = fdot2(w[3][q * 4 + 0], hv0, ao);
            ai = fdot2(w[0][q * 4 + 1], hv1, ai);
            af = fdot2(w[1][q * 4 + 1], hv1, af);
            ag = fdot2(w[2][q * 4 + 1], hv1, ag);
            ao = fdot2(w[3][q * 4 + 1], hv1, ao);
            ai = fdot2(w[0][q * 4 + 2], hv2, ai);
            af = fdot2(w[1][q * 4 + 2], hv2, af);
            ag = fdot2(w[2][q * 4 + 2], hv2, ag);
            ao = fdot2(w[3][q * 4 + 2], hv2, ao);
            ai = fdot2(w[0][q * 4 + 3], hv3, ai);
            af = fdot2(w[1][q * 4 + 3], hv3, af);
            ag = fdot2(w[2][q * 4 + 3], hv3, ag);
            ao = fdot2(w[3][q * 4 + 3], hv3, ao);
        }

        float i_ = sigm(ai);
        float f_ = sigm(af);
        float g_ = tanhr(ag);
        float o_ = sigm(ao);
        c = f_ * c + i_ * g_;
        h = o_ * tanhr(c);

        // publish h[L] for next step; single wave => lockstep, no barrier
        __builtin_amdgcn_wave_barrier();
        hb16[L] = (half1)h;
        __builtin_amdgcn_wave_barrier();

        pu = pn;
    }

    // logits[b] = sum_L h[L] * W_fc[L] + b_fc
    float contrib = h * Wfc[L];
#pragma unroll
    for (int off = 32; off > 0; off >>= 1) contrib += __shfl_down(contrib, off, 64);
    if (L == 0) {
        float z = contrib + bfc[0];
        logits[b] = z;
        // fused BCEWithLogits term: -(PW*t*logsig(z) + (1-t)*logsig(-z)) / B
        float tg = targets[b];
        float e = EXP2F(-1.44269504f * fabsf(z));
        float lsp = fminf(z, 0.0f) - log1pf(e);
        float lsn = lsp - z;
        float term = -(POS_W * tg * lsp + (1.0f - tg) * lsn) * (1.0f / (float)B_);
        atomicAdd(loss_slot, term);
    }
}

// ---------------------------------------------------------------------------
extern "C" void kernel_launch(void* const* d_in, const int* in_sizes, int n_in,
                              void* d_out, int out_size, void* d_ws, size_t ws_size,
                              hipStream_t stream) {
    const int* x = (const int*)d_in[0];
    const float* targets = (const float*)d_in[1];
    const float* emb = (const float*)d_in[2];
    const float* Wih = (const float*)d_in[3];
    const float* Whh = (const float*)d_in[4];
    const float* bih = (const float*)d_in[5];
    const float* bhh = (const float*)d_in[6];
    const float* Wfc = (const float*)d_in[7];
    const float* bfc = (const float*)d_in[8];
    float* out = (float*)d_out;  // [0..2047] logits, [2048] loss

    float* proj = (float*)d_ws;                               // 128*256*4 = 128 KiB
    uint32_t* whh = (uint32_t*)((char*)d_ws + 128 * 1024);    // 8192*4    = 32 KiB

    k_prep<<<dim3(V_ + 32), dim3(256), 0, stream>>>(emb, Wih, bih, bhh, Whh, proj, whh,
                                                    out + B_);
    k_lstm<<<dim3(B_), dim3(64), 0, stream>>>(x, whh, proj, Wfc, bfc, targets, out,
                                              out + B_);
}